// Round 4
// baseline (229.662 us; speedup 1.0000x reference)
//
#include <hip/hip_runtime.h>

// KNN k-th smallest distance, two-pass threshold-filter MFMA version, v2.
// dist = sqrt(2 - 2*dot(zn,rn)); sorted(dist)[k] == (k+1)-th LARGEST dot.
//  1) normalize_bf16: fused z+ref rows -> L2-normalized bf16
//  2) knn_pass<1>:  MFMA dots, epilogue = per-(row,chunk,lane16) subset MAX
//     (subsets partition the refs -> 11th largest of the 1024 subset maxes is
//      a valid lower bound T on the true 11th-largest dot)
//  3) knn_threshold: per row, exact 11th-largest of 1024 subset maxes -> T
//  4) knn_pass<2>:  MFMA dots again, keep v >= T[row] via atomic append
//  5) knn_final: exact 11th-largest of survivors -> dist
//
// v2 structure: A-fragments live in registers (loaded straight from global,
// loop-invariant); LDS holds ONLY the B tile, double-buffered, ONE barrier
// per 64-ref tile (write next buffer while others may still read current —
// disjoint buffers make that safe; the barrier both publishes the writes and
// proves all reads of the old buffer finished). 34.8 KB LDS -> 4 blocks/CU.

#define D_DIM 128
#define TQ 128         // queries per block (4 waves x 2 row-tiles x 16 rows)
#define BR 64          // refs per LDS tile
#define NCH 64         // ref chunks (grid.y); 16*64 = 1024 blocks = 4/CU
#define NSUB (NCH * 16) // subsets per row = 1024
#define CAP 256        // survivor capacity per row
#define ASTR 136       // LDS row stride (bf16); lane-bank = ln*4+... -> 2-way max (free)

typedef __bf16 bf16_t;
typedef bf16_t bf16x8 __attribute__((ext_vector_type(8)));
typedef float f32x4 __attribute__((ext_vector_type(4)));

__device__ __forceinline__ unsigned short f2bf(float f) {
    unsigned u = __float_as_uint(f);
    return (unsigned short)((u + 0x7fffu + ((u >> 16) & 1u)) >> 16);  // RNE
}

__global__ __launch_bounds__(256) void normalize_bf16(
    const float* __restrict__ z, const float* __restrict__ ref,
    unsigned short* __restrict__ zb, unsigned short* __restrict__ rb,
    int N, int M)
{
    const int w = threadIdx.x >> 6;
    const int l = threadIdx.x & 63;
    const int row = blockIdx.x * 4 + w;
    if (row >= N + M) return;
    const float* in; unsigned short* out; int r;
    if (row < N) { in = z;   out = zb; r = row; }
    else         { in = ref; out = rb; r = row - N; }
    const float2 v = ((const float2*)in)[(size_t)r * 64 + l];
    float ss = v.x * v.x + v.y * v.y;
    #pragma unroll
    for (int off = 32; off > 0; off >>= 1) ss += __shfl_xor(ss, off);
    const float inv = rsqrtf(ss);
    ushort2 o; o.x = f2bf(v.x * inv); o.y = f2bf(v.y * inv);
    ((ushort2*)out)[(size_t)r * 64 + l] = o;
}

// PASS==1: write subset maxes.  PASS==2: filter vs T, append survivors.
template <int PASS>
__global__ __launch_bounds__(256, 4) void knn_pass(
    const unsigned short* __restrict__ zb, const unsigned short* __restrict__ rb,
    float* __restrict__ maxes, const float* __restrict__ T,
    int* __restrict__ cnt, float* __restrict__ surv,
    int N, int M, int chunk)
{
    __shared__ __align__(16) unsigned short Bt[2][BR * ASTR];  // 2 x 17408 B

    const int t = threadIdx.x;
    const int lane = t & 63;
    const int w = t >> 6;          // wave -> query rows w*32 .. w*32+31
    const int quad = lane >> 4;
    const int ln = lane & 15;
    const int qbase = blockIdx.x * TQ;
    const int c0 = blockIdx.y * chunk;
    const int c1 = min(c0 + chunk, M);

    // A fragments straight from global (loop-invariant). Lane (ln,quad) holds
    // A[m=ln][k=quad*8+j] for row w*32+rt*16+ln, k-step ks.
    bf16x8 afr[2][4];
    #pragma unroll
    for (int rt = 0; rt < 2; ++rt)
        #pragma unroll
        for (int ks = 0; ks < 4; ++ks)
            afr[rt][ks] = *(const bf16x8*)
                &zb[(size_t)(qbase + w * 32 + rt * 16 + ln) * D_DIM + ks * 32 + quad * 8];

    float mx[2][4];   // pass1: per-lane subset max, rows rt*16+quad*4+r
    float tr[2][4];   // pass2: per-row thresholds
    #pragma unroll
    for (int rt = 0; rt < 2; ++rt)
        #pragma unroll
        for (int r = 0; r < 4; ++r) {
            if (PASS == 1) mx[rt][r] = -3.0f;
            else tr[rt][r] = T[qbase + w * 32 + rt * 16 + quad * 4 + r];
        }

    // Staging: 64 refs x 16 x 16B = 1024 uint4, 4 per thread.
    uint4 st[4];
    int sr[4], sc[4];
    #pragma unroll
    for (int i = 0; i < 4; ++i) {
        int idx = t + 256 * i;
        sr[i] = idx >> 4; sc[i] = idx & 15;
    }
    auto load_tile = [&](int s0) {
        #pragma unroll
        for (int i = 0; i < 4; ++i) {
            int g = s0 + sr[i]; if (g > M - 1) g = M - 1;   // clamp; masked later
            st[i] = *(const uint4*)&rb[(size_t)g * D_DIM + sc[i] * 8];
        }
    };
    auto write_tile = [&](int buf) {
        #pragma unroll
        for (int i = 0; i < 4; ++i)
            *(uint4*)&Bt[buf][sr[i] * ASTR + sc[i] * 8] = st[i];
    };

    load_tile(c0);
    write_tile(0);
    __syncthreads();

    int cur = 0;
    for (int s0 = c0; ; ) {
        const int s_next = s0 + BR;
        const bool more = s_next < c1;
        if (more) load_tile(s_next);          // issue loads early (latency overlap)

        f32x4 acc[2][4];
        #pragma unroll
        for (int rt = 0; rt < 2; ++rt)
            #pragma unroll
            for (int ct = 0; ct < 4; ++ct) acc[rt][ct] = (f32x4){0.f,0.f,0.f,0.f};

        #pragma unroll
        for (int ks = 0; ks < 4; ++ks) {
            #pragma unroll
            for (int ct = 0; ct < 4; ++ct) {
                bf16x8 bfr = *(const bf16x8*)
                    &Bt[cur][(ct * 16 + ln) * ASTR + ks * 32 + quad * 8];
                #pragma unroll
                for (int rt = 0; rt < 2; ++rt)
                    acc[rt][ct] = __builtin_amdgcn_mfma_f32_16x16x32_bf16(
                        afr[rt][ks], bfr, acc[rt][ct], 0, 0, 0);
            }
        }

        // Epilogue. Lane's column g uniform across rt/r for fixed ct.
        #pragma unroll
        for (int ct = 0; ct < 4; ++ct) {
            int g = s0 + ct * 16 + ln;
            if (g < c1) {
                if (PASS == 1) {
                    #pragma unroll
                    for (int rt = 0; rt < 2; ++rt)
                        #pragma unroll
                        for (int r = 0; r < 4; ++r)
                            mx[rt][r] = fmaxf(mx[rt][r], acc[rt][ct][r]);
                } else {
                    #pragma unroll
                    for (int rt = 0; rt < 2; ++rt)
                        #pragma unroll
                        for (int r = 0; r < 4; ++r) {
                            float v = acc[rt][ct][r];
                            if (v >= tr[rt][r]) {   // rare (~30 hits / 50000)
                                int row = qbase + w * 32 + rt * 16 + quad * 4 + r;
                                int slot = atomicAdd(&cnt[row], 1);
                                if (slot < CAP) surv[(size_t)row * CAP + slot] = v;
                            }
                        }
                }
            }
        }

        if (!more) break;
        write_tile(cur ^ 1);   // idle buffer: no reader until after the barrier
        __syncthreads();       // publishes writes + proves reads of cur are done
        cur ^= 1; s0 = s_next;
    }

    if (PASS == 1) {
        #pragma unroll
        for (int rt = 0; rt < 2; ++rt)
            #pragma unroll
            for (int r = 0; r < 4; ++r) {
                int row = qbase + w * 32 + rt * 16 + quad * 4 + r;
                maxes[(size_t)row * NSUB + blockIdx.y * 16 + ln] = mx[rt][r];
            }
    }
}

// 4 rows per block, one wave each. Exact (k+1)-th largest of NSUB maxes -> T.
__global__ __launch_bounds__(256) void knn_threshold(
    const float* __restrict__ maxes, const int* __restrict__ kp,
    float* __restrict__ T, int* __restrict__ cnt)
{
    const int row = blockIdx.x * 4 + (threadIdx.x >> 6);
    const int t = threadIdx.x & 63;
    float v[NSUB / 64];   // 16
    float lm = -3.0f;
    #pragma unroll
    for (int i = 0; i < NSUB / 64; ++i) {
        v[i] = maxes[(size_t)row * NSUB + t + 64 * i];
        lm = fmaxf(lm, v[i]);
    }
    const int kk = *kp;   // 10
    float cur = -3.0f;
    for (int it = 0; it <= kk; ++it) {
        float m = lm;
        #pragma unroll
        for (int off = 32; off > 0; off >>= 1) m = fmaxf(m, __shfl_xor(m, off));
        cur = m;
        unsigned long long b = __ballot(lm == m);
        if ((int)(__ffsll(b) - 1) == t) {
            bool rm = false;
            lm = -3.0f;
            #pragma unroll
            for (int i = 0; i < NSUB / 64; ++i) {
                if (!rm && v[i] == m) { v[i] = -3.0f; rm = true; }
                lm = fmaxf(lm, v[i]);
            }
        }
    }
    if (t == 0) { T[row] = cur; cnt[row] = 0; }
}

// 4 rows per block, one wave each. Exact (k+1)-th largest of survivors.
__global__ __launch_bounds__(256) void knn_final(
    const float* __restrict__ surv, const int* __restrict__ cnt,
    const int* __restrict__ kp, float* __restrict__ out)
{
    const int row = blockIdx.x * 4 + (threadIdx.x >> 6);
    const int t = threadIdx.x & 63;
    int c = cnt[row]; if (c > CAP) c = CAP;
    float v[CAP / 64];   // 4
    float lm = -3.0f;
    #pragma unroll
    for (int i = 0; i < CAP / 64; ++i) {
        int idx = t + 64 * i;
        v[i] = (idx < c) ? surv[(size_t)row * CAP + idx] : -3.0f;
        lm = fmaxf(lm, v[i]);
    }
    const int kk = *kp;
    float cur = -3.0f;
    for (int it = 0; it <= kk; ++it) {
        float m = lm;
        #pragma unroll
        for (int off = 32; off > 0; off >>= 1) m = fmaxf(m, __shfl_xor(m, off));
        cur = m;
        unsigned long long b = __ballot(lm == m);
        if ((int)(__ffsll(b) - 1) == t) {
            bool rm = false;
            lm = -3.0f;
            #pragma unroll
            for (int i = 0; i < CAP / 64; ++i) {
                if (!rm && v[i] == m) { v[i] = -3.0f; rm = true; }
                lm = fmaxf(lm, v[i]);
            }
        }
    }
    if (t == 0) out[row] = sqrtf(fmaxf(2.0f - 2.0f * cur, 1e-12f));
}

extern "C" void kernel_launch(void* const* d_in, const int* in_sizes, int n_in,
                              void* d_out, int out_size, void* d_ws, size_t ws_size,
                              hipStream_t stream) {
    const float* z   = (const float*)d_in[0];
    const float* ref = (const float*)d_in[1];
    const int*   kp  = (const int*)d_in[2];
    float* out = (float*)d_out;

    const int N = in_sizes[0] / D_DIM;   // 2048
    const int M = in_sizes[1] / D_DIM;   // 50000

    unsigned short* zbuf = (unsigned short*)d_ws;             // N*128 bf16
    unsigned short* rbuf = zbuf + (size_t)N * D_DIM;          // M*128 bf16
    float* maxes = (float*)(rbuf + (size_t)M * D_DIM);        // N*NSUB f32 (8MB)
    float* T     = maxes + (size_t)N * NSUB;                  // N f32
    int*   cnt   = (int*)(T + N);                             // N i32
    float* surv  = (float*)(cnt + N);                         // N*CAP f32 (2MB)

    normalize_bf16<<<(N + M + 3) / 4, 256, 0, stream>>>(z, ref, zbuf, rbuf, N, M);

    const int chunk = (M + NCH - 1) / NCH;    // 782
    dim3 grid(N / TQ, NCH);                   // 16 x 64 = 1024 blocks = 4/CU

    knn_pass<1><<<grid, 256, 0, stream>>>(zbuf, rbuf, maxes, nullptr,
                                          nullptr, nullptr, N, M, chunk);
    knn_threshold<<<N / 4, 256, 0, stream>>>(maxes, kp, T, cnt);
    knn_pass<2><<<grid, 256, 0, stream>>>(zbuf, rbuf, nullptr, T,
                                          cnt, surv, N, M, chunk);
    knn_final<<<N / 4, 256, 0, stream>>>(surv, cnt, kp, out);
}

// Round 5
// 186.132 us; speedup vs baseline: 1.2339x; 1.2339x over previous
//
#include <hip/hip_runtime.h>

// KNN k-th smallest distance, two-pass threshold-filter MFMA version, v3.
// dist = sqrt(2 - 2*dot(zn,rn)); sorted(dist)[k] == (k+1)-th LARGEST dot.
//  1) normalize_bf16: fused z+ref rows -> L2-normalized bf16
//  2) knn_pass<1>:  MFMA dots, epilogue = per-(row,chunk,lane16) subset MAX
//     (subsets partition the refs -> 11th largest of the 1024 subset maxes is
//      a valid lower bound T on the true 11th-largest dot)
//  3) knn_threshold: per row, exact 11th-largest of 1024 subset maxes -> T
//  4) knn_pass<2>:  MFMA dots again, keep v >= T[row] via atomic append
//  5) knn_final: exact 11th-largest of survivors -> dist
//
// v3: B staged via __builtin_amdgcn_global_load_lds (16B) into a
// fragment-blocked LDS layout — slot j=(ct*4+ks)*64+quad*16+ln holds the 16B
// B-fragment piece for (ref=ct*16+ln, k=ks*32+quad*8). Wave-contiguous lane
// writes (HW constraint) AND minimal-conflict ds_read_b128. Double-buffered,
// ONE barrier per 64-ref tile (vmcnt drain sits after the compute phase).
// NO __launch_bounds__ min-waves: round 4 showed (256,4) caps the UNIFIED
// VGPR+AGPR budget at 128 -> 64 arch VGPRs -> scratch spills (177MB writes).

#define D_DIM 128
#define TQ 128         // queries per block (4 waves x 2 row-tiles x 16 rows)
#define BR 64          // refs per LDS tile
#define NCH 64         // ref chunks (grid.y); 16*64 = 1024 blocks = 4/CU
#define NSUB (NCH * 16) // subsets per row = 1024
#define CAP 256        // survivor capacity per row

typedef __bf16 bf16_t;
typedef bf16_t bf16x8 __attribute__((ext_vector_type(8)));
typedef float f32x4 __attribute__((ext_vector_type(4)));

__device__ __forceinline__ unsigned short f2bf(float f) {
    unsigned u = __float_as_uint(f);
    return (unsigned short)((u + 0x7fffu + ((u >> 16) & 1u)) >> 16);  // RNE
}

__device__ __forceinline__ void gld_lds16(const void* g, void* l) {
    __builtin_amdgcn_global_load_lds(
        (const __attribute__((address_space(1))) void*)g,
        (__attribute__((address_space(3))) void*)l, 16, 0, 0);
}

__global__ __launch_bounds__(256) void normalize_bf16(
    const float* __restrict__ z, const float* __restrict__ ref,
    unsigned short* __restrict__ zb, unsigned short* __restrict__ rb,
    int N, int M)
{
    const int w = threadIdx.x >> 6;
    const int l = threadIdx.x & 63;
    const int row = blockIdx.x * 4 + w;
    if (row >= N + M) return;
    const float* in; unsigned short* out; int r;
    if (row < N) { in = z;   out = zb; r = row; }
    else         { in = ref; out = rb; r = row - N; }
    const float2 v = ((const float2*)in)[(size_t)r * 64 + l];
    float ss = v.x * v.x + v.y * v.y;
    #pragma unroll
    for (int off = 32; off > 0; off >>= 1) ss += __shfl_xor(ss, off);
    const float inv = rsqrtf(ss);
    ushort2 o; o.x = f2bf(v.x * inv); o.y = f2bf(v.y * inv);
    ((ushort2*)out)[(size_t)r * 64 + l] = o;
}

// PASS==1: write subset maxes.  PASS==2: filter vs T, append survivors.
template <int PASS>
__global__ __launch_bounds__(256) void knn_pass(
    const unsigned short* __restrict__ zb, const unsigned short* __restrict__ rb,
    float* __restrict__ maxes, const float* __restrict__ T,
    int* __restrict__ cnt, float* __restrict__ surv,
    int N, int M, int chunk)
{
    // Fragment-blocked B tiles: 1024 slots x 16 B each, double-buffered.
    __shared__ __align__(16) unsigned short Bt[2][BR * D_DIM];  // 2 x 16384 B

    const int t = threadIdx.x;
    const int lane = t & 63;
    const int w = t >> 6;          // wave -> query rows w*32 .. w*32+31
    const int quad = lane >> 4;
    const int ln = lane & 15;
    const int qbase = blockIdx.x * TQ;
    const int c0 = blockIdx.y * chunk;
    const int c1 = min(c0 + chunk, M);

    // A fragments straight from global (loop-invariant). Lane (ln,quad) holds
    // A[m=ln][k=quad*8+j] for row w*32+rt*16+ln, k-step ks.
    bf16x8 afr[2][4];
    #pragma unroll
    for (int rt = 0; rt < 2; ++rt)
        #pragma unroll
        for (int ks = 0; ks < 4; ++ks)
            afr[rt][ks] = *(const bf16x8*)
                &zb[(size_t)(qbase + w * 32 + rt * 16 + ln) * D_DIM + ks * 32 + quad * 8];

    float mx[2][4];   // pass1: per-lane subset max, rows rt*16+quad*4+r
    float tr[2][4];   // pass2: per-row thresholds
    #pragma unroll
    for (int rt = 0; rt < 2; ++rt)
        #pragma unroll
        for (int r = 0; r < 4; ++r) {
            if (PASS == 1) mx[rt][r] = -3.0f;
            else tr[rt][r] = T[qbase + w * 32 + rt * 16 + quad * 4 + r];
        }

    // Async staging: thread t owns slots j = t + 256*i (i=0..3); slot j
    // decomposes as ctks=j>>6, quad=(j>>4)&3, ln=j&15 and sources the 16B at
    // rb[(s0 + ct*16+ln)*128 + ks*32 + quad*8]. Per-lane global pointers are
    // advanced by BR*128 elements per tile; LDS destination is wave-uniform
    // (w,i) base + lane*16 (HW-added). Tail overread (<= 34 rows past M)
    // stays inside d_ws and is masked at the epilogue.
    const unsigned short* gp[4];
    #pragma unroll
    for (int i = 0; i < 4; ++i) {
        int j = t + 256 * i;
        int sct = j >> 8, sks = (j >> 6) & 3, sq = (j >> 4) & 3, sl = j & 15;
        gp[i] = rb + (size_t)(c0 + sct * 16 + sl) * D_DIM + sks * 32 + sq * 8;
    }
    auto issue_tile = [&](int buf) {
        #pragma unroll
        for (int i = 0; i < 4; ++i) {
            gld_lds16(gp[i], &Bt[buf][(i * 256 + w * 64) * 8]);
            gp[i] += BR * D_DIM;
        }
    };

    issue_tile(0);
    __syncthreads();   // drain prologue loads

    int cur = 0;
    for (int s0 = c0; ; ) {
        const int s_next = s0 + BR;
        const bool more = s_next < c1;
        if (more) issue_tile(cur ^ 1);   // async into idle buffer; lands by next barrier

        f32x4 acc[2][4];
        #pragma unroll
        for (int rt = 0; rt < 2; ++rt)
            #pragma unroll
            for (int ct = 0; ct < 4; ++ct) acc[rt][ct] = (f32x4){0.f,0.f,0.f,0.f};

        #pragma unroll
        for (int ks = 0; ks < 4; ++ks) {
            #pragma unroll
            for (int ct = 0; ct < 4; ++ct) {
                bf16x8 bfr = *(const bf16x8*)
                    &Bt[cur][((ct * 4 + ks) * 64 + quad * 16 + ln) * 8];
                #pragma unroll
                for (int rt = 0; rt < 2; ++rt)
                    acc[rt][ct] = __builtin_amdgcn_mfma_f32_16x16x32_bf16(
                        afr[rt][ks], bfr, acc[rt][ct], 0, 0, 0);
            }
        }

        // Epilogue. Lane's column g uniform across rt/r for fixed ct.
        #pragma unroll
        for (int ct = 0; ct < 4; ++ct) {
            int g = s0 + ct * 16 + ln;
            if (g < c1) {
                if (PASS == 1) {
                    #pragma unroll
                    for (int rt = 0; rt < 2; ++rt)
                        #pragma unroll
                        for (int r = 0; r < 4; ++r)
                            mx[rt][r] = fmaxf(mx[rt][r], acc[rt][ct][r]);
                } else {
                    #pragma unroll
                    for (int rt = 0; rt < 2; ++rt)
                        #pragma unroll
                        for (int r = 0; r < 4; ++r) {
                            float v = acc[rt][ct][r];
                            if (v >= tr[rt][r]) {   // rare (~30 hits / 50000)
                                int row = qbase + w * 32 + rt * 16 + quad * 4 + r;
                                int slot = atomicAdd(&cnt[row], 1);
                                if (slot < CAP) surv[(size_t)row * CAP + slot] = v;
                            }
                        }
                }
            }
        }

        if (!more) break;
        __syncthreads();   // drains async loads into cur^1 + all reads of cur done
        cur ^= 1; s0 = s_next;
    }

    if (PASS == 1) {
        #pragma unroll
        for (int rt = 0; rt < 2; ++rt)
            #pragma unroll
            for (int r = 0; r < 4; ++r) {
                int row = qbase + w * 32 + rt * 16 + quad * 4 + r;
                maxes[(size_t)row * NSUB + blockIdx.y * 16 + ln] = mx[rt][r];
            }
    }
}

// 4 rows per block, one wave each. Exact (k+1)-th largest of NSUB maxes -> T.
__global__ __launch_bounds__(256) void knn_threshold(
    const float* __restrict__ maxes, const int* __restrict__ kp,
    float* __restrict__ T, int* __restrict__ cnt)
{
    const int row = blockIdx.x * 4 + (threadIdx.x >> 6);
    const int t = threadIdx.x & 63;
    float v[NSUB / 64];   // 16
    float lm = -3.0f;
    #pragma unroll
    for (int i = 0; i < NSUB / 64; ++i) {
        v[i] = maxes[(size_t)row * NSUB + t + 64 * i];
        lm = fmaxf(lm, v[i]);
    }
    const int kk = *kp;   // 10
    float cur = -3.0f;
    for (int it = 0; it <= kk; ++it) {
        float m = lm;
        #pragma unroll
        for (int off = 32; off > 0; off >>= 1) m = fmaxf(m, __shfl_xor(m, off));
        cur = m;
        unsigned long long b = __ballot(lm == m);
        if ((int)(__ffsll(b) - 1) == t) {
            bool rm = false;
            lm = -3.0f;
            #pragma unroll
            for (int i = 0; i < NSUB / 64; ++i) {
                if (!rm && v[i] == m) { v[i] = -3.0f; rm = true; }
                lm = fmaxf(lm, v[i]);
            }
        }
    }
    if (t == 0) { T[row] = cur; cnt[row] = 0; }
}

// 4 rows per block, one wave each. Exact (k+1)-th largest of survivors.
__global__ __launch_bounds__(256) void knn_final(
    const float* __restrict__ surv, const int* __restrict__ cnt,
    const int* __restrict__ kp, float* __restrict__ out)
{
    const int row = blockIdx.x * 4 + (threadIdx.x >> 6);
    const int t = threadIdx.x & 63;
    int c = cnt[row]; if (c > CAP) c = CAP;
    float v[CAP / 64];   // 4
    float lm = -3.0f;
    #pragma unroll
    for (int i = 0; i < CAP / 64; ++i) {
        int idx = t + 64 * i;
        v[i] = (idx < c) ? surv[(size_t)row * CAP + idx] : -3.0f;
        lm = fmaxf(lm, v[i]);
    }
    const int kk = *kp;
    float cur = -3.0f;
    for (int it = 0; it <= kk; ++it) {
        float m = lm;
        #pragma unroll
        for (int off = 32; off > 0; off >>= 1) m = fmaxf(m, __shfl_xor(m, off));
        cur = m;
        unsigned long long b = __ballot(lm == m);
        if ((int)(__ffsll(b) - 1) == t) {
            bool rm = false;
            lm = -3.0f;
            #pragma unroll
            for (int i = 0; i < CAP / 64; ++i) {
                if (!rm && v[i] == m) { v[i] = -3.0f; rm = true; }
                lm = fmaxf(lm, v[i]);
            }
        }
    }
    if (t == 0) out[row] = sqrtf(fmaxf(2.0f - 2.0f * cur, 1e-12f));
}

extern "C" void kernel_launch(void* const* d_in, const int* in_sizes, int n_in,
                              void* d_out, int out_size, void* d_ws, size_t ws_size,
                              hipStream_t stream) {
    const float* z   = (const float*)d_in[0];
    const float* ref = (const float*)d_in[1];
    const int*   kp  = (const int*)d_in[2];
    float* out = (float*)d_out;

    const int N = in_sizes[0] / D_DIM;   // 2048
    const int M = in_sizes[1] / D_DIM;   // 50000

    unsigned short* zbuf = (unsigned short*)d_ws;             // N*128 bf16
    unsigned short* rbuf = zbuf + (size_t)N * D_DIM;          // M*128 bf16
    float* maxes = (float*)(rbuf + (size_t)M * D_DIM);        // N*NSUB f32 (8MB)
    float* T     = maxes + (size_t)N * NSUB;                  // N f32
    int*   cnt   = (int*)(T + N);                             // N i32
    float* surv  = (float*)(cnt + N);                         // N*CAP f32 (2MB)

    normalize_bf16<<<(N + M + 3) / 4, 256, 0, stream>>>(z, ref, zbuf, rbuf, N, M);

    const int chunk = (M + NCH - 1) / NCH;    // 782
    dim3 grid(N / TQ, NCH);                   // 16 x 64 = 1024 blocks = 4/CU

    knn_pass<1><<<grid, 256, 0, stream>>>(zbuf, rbuf, maxes, nullptr,
                                          nullptr, nullptr, N, M, chunk);
    knn_threshold<<<N / 4, 256, 0, stream>>>(maxes, kp, T, cnt);
    knn_pass<2><<<grid, 256, 0, stream>>>(zbuf, rbuf, nullptr, T,
                                          cnt, surv, N, M, chunk);
    knn_final<<<N / 4, 256, 0, stream>>>(surv, cnt, kp, out);
}